// Round 1
// baseline (306.771 us; speedup 1.0000x reference)
//
#include <hip/hip_runtime.h>
#include <hip/hip_bf16.h>
#include <stdint.h>

#define NTOK 196
#define NB   64
#define CCH  512
#define NHEAD 16
#define HD   32
#define HID  2048
#define MTOT (NB * NTOK)   // 12544

typedef __attribute__((ext_vector_type(8))) short  short8v;
typedef __attribute__((ext_vector_type(4))) float  float4v;

// ---------------- helpers ----------------

__device__ __forceinline__ void mfma16x16(float4v& d, short8v a, short8v b) {
  asm("v_mfma_f32_16x16x32_bf16 %0, %1, %2, %0" : "+v"(d) : "v"(a), "v"(b));
}

__device__ __forceinline__ void gload_lds16(const void* gsrc, void* ldst) {
  __builtin_amdgcn_global_load_lds(
      (const __attribute__((address_space(1))) unsigned int*)gsrc,
      (__attribute__((address_space(3))) unsigned int*)ldst, 16, 0, 0);
}

__device__ __forceinline__ int swz4(int r) { return (r ^ (r >> 2)) & 3; }

// ---------------- prep: BN constants ----------------

__global__ void prep_consts(const float* __restrict__ bn_g, const float* __restrict__ bn_b,
                            const float* __restrict__ bn_m, const float* __restrict__ bn_v,
                            const float* __restrict__ fbn_g, const float* __restrict__ fbn_b,
                            const float* __restrict__ fbn_m, const float* __restrict__ fbn_v,
                            float* __restrict__ cst) {
  int c = blockIdx.x * blockDim.x + threadIdx.x;
  if (c < CCH) {
    float i1 = bn_g[c] * rsqrtf(bn_v[c] + 1e-5f);
    cst[c] = i1;
    cst[512 + c] = bn_b[c] - bn_m[c] * i1;
    float i2 = fbn_g[c] * rsqrtf(fbn_v[c] + 1e-5f);
    cst[1024 + c] = i2;
    cst[1536 + c] = fbn_b[c] - fbn_m[c] * i2;
  }
}

// ---------------- weights fp32 -> bf16 ----------------

__global__ void cvt_weights(const float* __restrict__ qkv_w, const float* __restrict__ proj_w,
                            const float* __restrict__ fc1_w, const float* __restrict__ fc2_w,
                            __hip_bfloat16* __restrict__ qkvb, __hip_bfloat16* __restrict__ projb,
                            __hip_bfloat16* __restrict__ fc1b, __hip_bfloat16* __restrict__ fc2b) {
  int i4 = blockIdx.x * blockDim.x + threadIdx.x;    // unit = 4 floats
  const int nq = 1536 * 512 / 4;   // 196608
  const int np = 512 * 512 / 4;    // 65536
  const int n1 = 2048 * 512 / 4;   // 262144
  const float* src;
  __hip_bfloat16* dst;
  int k;
  if (i4 < nq)                { src = qkv_w;  dst = qkvb;  k = i4; }
  else if (i4 < nq + np)      { src = proj_w; dst = projb; k = i4 - nq; }
  else if (i4 < nq + np + n1) { src = fc1_w;  dst = fc1b;  k = i4 - nq - np; }
  else                        { src = fc2_w;  dst = fc2b;  k = i4 - nq - np - n1; }
  float4v v = *(const float4v*)(src + 4 * (size_t)k);
  #pragma unroll
  for (int l = 0; l < 4; ++l) dst[4 * (size_t)k + l] = __float2bfloat16(v[l]);
}

// ---------------- transpose NCHW(ch-major) -> token-major bf16 (optional BN affine) ----------------

template<bool AFFINE>
__global__ __launch_bounds__(256) void transpose_cn(
    const void* __restrict__ in, __hip_bfloat16* __restrict__ out,
    const float* __restrict__ s, const float* __restrict__ t) {
  __shared__ float tile[32][33];
  const int n0 = blockIdx.x * 32;
  const int c0 = blockIdx.y * 32;
  const int b  = blockIdx.z;
  const int j = threadIdx.x & 31, i = threadIdx.x >> 5;   // i in 0..7
  #pragma unroll
  for (int p = 0; p < 4; ++p) {
    int cc = c0 + i + p * 8;
    int n = n0 + j;
    if (n < NTOK) {
      float v;
      if (AFFINE)
        v = ((const float*)in)[((size_t)b * CCH + cc) * NTOK + n] * s[cc] + t[cc];
      else
        v = __bfloat162float(((const __hip_bfloat16*)in)[((size_t)b * CCH + cc) * NTOK + n]);
      tile[i + p * 8][j] = v;
    }
  }
  __syncthreads();
  #pragma unroll
  for (int p = 0; p < 4; ++p) {
    int n = n0 + i + p * 8;
    int cc = c0 + j;
    if (n < NTOK)
      out[((size_t)b * NTOK + n) * CCH + cc] = __float2bfloat16(tile[j][i + p * 8]);
  }
}

// ---------------- GEMM: C[M,N] = A[M,K] * B[N,K]^T, bf16 in, fp32 acc ----------------
// EPI: 0 = plain bf16 store (QKV)    1 = proj: x1 = x + ls1*(v+bias) (NCHW fp32)
//      2 = fc1: gelu(v+bias) bf16    3 = fc2: out = x1 + ls2*(v+bias) (NCHW fp32)

template<int EPI>
__global__ __launch_bounds__(256, 2) void gemm_bt(
    const __hip_bfloat16* __restrict__ A, const __hip_bfloat16* __restrict__ Bw,
    int N, int K,
    __hip_bfloat16* __restrict__ outb, float* __restrict__ outf,
    const float* __restrict__ bias, const float* __restrict__ ls,
    const float* __restrict__ resid) {
  __shared__ char lds[32768];   // 2 bufs x (A 8KB + B 8KB)
  const int tid  = threadIdx.x;
  const int lane = tid & 63;
  const int wave = tid >> 6;
  const int m0 = blockIdx.x * 128;
  const int n0 = blockIdx.y * 128;
  const int wm = (wave >> 1) * 64;
  const int wn = (wave & 1) * 64;
  const int KT = K >> 5;

  float4v acc[4][4] = {};

  auto stage = [&](int buf, int kt) {
    const int kb = kt * 32;
    char* base = lds + buf * 16384;
    #pragma unroll
    for (int i = 0; i < 2; ++i) {
      int L = i * 4096 + tid * 16;
      int row = L >> 6;
      int kc = ((L >> 4) & 3) ^ swz4(row);
      gload_lds16(A + (size_t)(m0 + row) * K + kb + kc * 8, base + L);
    }
    #pragma unroll
    for (int i = 0; i < 2; ++i) {
      int L = i * 4096 + tid * 16;
      int row = L >> 6;
      int kc = ((L >> 4) & 3) ^ swz4(row);
      gload_lds16(Bw + (size_t)(n0 + row) * K + kb + kc * 8, base + 8192 + L);
    }
  };

  stage(0, 0);
  int cur = 0;
  for (int kt = 0; kt < KT; ++kt) {
    __syncthreads();                       // drains vmcnt: buf[cur] staged & prior reads done
    if (kt + 1 < KT) stage(cur ^ 1, kt + 1);
    const char* bA = lds + cur * 16384;
    const char* bB = bA + 8192;
    short8v av[4], bv[4];
    #pragma unroll
    for (int t = 0; t < 4; ++t) {
      int row = wm + t * 16 + (lane & 15);
      int pc = (lane >> 4) ^ swz4(row);
      av[t] = *(const short8v*)(bA + row * 64 + pc * 16);
    }
    #pragma unroll
    for (int t = 0; t < 4; ++t) {
      int row = wn + t * 16 + (lane & 15);
      int pc = (lane >> 4) ^ swz4(row);
      bv[t] = *(const short8v*)(bB + row * 64 + pc * 16);
    }
    #pragma unroll
    for (int i = 0; i < 4; ++i)
      #pragma unroll
      for (int j = 0; j < 4; ++j)
        mfma16x16(acc[i][j], av[i], bv[j]);
    cur ^= 1;
  }
  asm volatile("s_nop 7\n\ts_nop 7");      // MFMA->VALU hazard guard

  #pragma unroll
  for (int i = 0; i < 4; ++i) {
    #pragma unroll
    for (int j = 0; j < 4; ++j) {
      #pragma unroll
      for (int r = 0; r < 4; ++r) {
        int m = m0 + wm + i * 16 + ((lane >> 4) << 2) + r;
        int n = n0 + wn + j * 16 + (lane & 15);
        float v = acc[i][j][r];
        if (EPI == 0) {
          outb[(size_t)m * N + n] = __float2bfloat16(v);
        } else if (EPI == 2) {
          float z = v + bias[n];
          float g = 0.5f * z * (1.0f + erff(z * 0.70710678118654752f));
          outb[(size_t)m * N + n] = __float2bfloat16(g);
        } else {
          int bb = m / NTOK, tt = m - bb * NTOK;
          size_t xi = ((size_t)bb * CCH + n) * NTOK + tt;
          outf[xi] = resid[xi] + ls[n] * (v + bias[n]);
        }
      }
    }
  }
}

// ---------------- attention: one block per (batch, head) ----------------

__global__ __launch_bounds__(256, 2) void attn_kernel(
    const __hip_bfloat16* __restrict__ qkv, __hip_bfloat16* __restrict__ o_t) {
  __shared__ char sQ[208 * 64];    // [208][32] bf16, chunk-swizzled rows
  __shared__ char sK[224 * 64];    // [224][32] bf16
  __shared__ char sV[32 * 448];    // V^T [32][224] bf16, chunk-swizzled
  __shared__ char sP[4][16 * 472]; // per-wave P [16][236] bf16 (stride 236 => conflict-free)
  const int tid  = threadIdx.x;
  const int lane = tid & 63;
  const int wave = tid >> 6;
  const int b = blockIdx.x >> 4;
  const int h = blockIdx.x & 15;
  const size_t qbase = (size_t)b * NTOK * 1536 + h * HD;

  {
    uint32_t* z = (uint32_t*)sQ;
    for (int i = tid; i < (208 * 64) / 4; i += 256) z[i] = 0u;
    z = (uint32_t*)sK;
    for (int i = tid; i < (224 * 64) / 4; i += 256) z[i] = 0u;
    z = (uint32_t*)sV;
    for (int i = tid; i < (32 * 448) / 4; i += 256) z[i] = 0u;
  }
  __syncthreads();

  for (int p = tid; p < NTOK * 4; p += 256) {
    int row = p >> 2, c = p & 3;
    const __hip_bfloat16* src = qkv + qbase + (size_t)row * 1536 + c * 8;
    short8v q = *(const short8v*)(src);
    short8v k = *(const short8v*)(src + 512);
    short8v v = *(const short8v*)(src + 1024);
    int pc = c ^ swz4(row);
    *(short8v*)(sQ + row * 64 + pc * 16) = q;
    *(short8v*)(sK + row * 64 + pc * 16) = k;
    #pragma unroll
    for (int j = 0; j < 8; ++j) {
      int d = c * 8 + j;
      int ch = (row >> 3) ^ swz4(d);
      *(uint16_t*)(sV + d * 448 + ch * 16 + (row & 7) * 2) = (uint16_t)v[j];
    }
  }
  __syncthreads();

  const float scale = 0.17677669529663687f;   // 1/sqrt(32)
  char* Pw = sP[wave];

  for (int mt = wave; mt < 13; mt += 4) {
    int qrow = mt * 16 + (lane & 15);
    int pcq = (lane >> 4) ^ swz4(qrow);
    short8v aq = *(const short8v*)(sQ + qrow * 64 + pcq * 16);

    float4v s[14];
    #pragma unroll
    for (int nt = 0; nt < 14; ++nt) {
      int krow = nt * 16 + (lane & 15);
      int pck = (lane >> 4) ^ swz4(krow);
      short8v bk = *(const short8v*)(sK + krow * 64 + pck * 16);
      s[nt] = float4v{0.f, 0.f, 0.f, 0.f};
      mfma16x16(s[nt], aq, bk);
    }
    asm volatile("s_nop 7\n\ts_nop 7");

    float mx[4] = {-INFINITY, -INFINITY, -INFINITY, -INFINITY};
    #pragma unroll
    for (int nt = 0; nt < 14; ++nt) {
      bool valid = (nt * 16 + (lane & 15)) < NTOK;
      #pragma unroll
      for (int r = 0; r < 4; ++r) {
        float v = valid ? s[nt][r] * scale : -INFINITY;
        s[nt][r] = v;
        mx[r] = fmaxf(mx[r], v);
      }
    }
    #pragma unroll
    for (int off = 1; off < 16; off <<= 1) {
      #pragma unroll
      for (int r = 0; r < 4; ++r) mx[r] = fmaxf(mx[r], __shfl_xor(mx[r], off));
    }
    float sum[4] = {0.f, 0.f, 0.f, 0.f};
    #pragma unroll
    for (int nt = 0; nt < 14; ++nt) {
      #pragma unroll
      for (int r = 0; r < 4; ++r) {
        float e = __expf(s[nt][r] - mx[r]);
        s[nt][r] = e;
        sum[r] += e;
      }
    }
    #pragma unroll
    for (int off = 1; off < 16; off <<= 1) {
      #pragma unroll
      for (int r = 0; r < 4; ++r) sum[r] += __shfl_xor(sum[r], off);
    }
    float rs[4];
    #pragma unroll
    for (int r = 0; r < 4; ++r) rs[r] = 1.0f / sum[r];

    #pragma unroll
    for (int nt = 0; nt < 14; ++nt) {
      int col = nt * 16 + (lane & 15);
      #pragma unroll
      for (int r = 0; r < 4; ++r) {
        int prow = ((lane >> 4) << 2) + r;
        *(__hip_bfloat16*)(Pw + prow * 472 + col * 2) = __float2bfloat16(s[nt][r] * rs[r]);
      }
    }

    float4v o0 = float4v{0.f, 0.f, 0.f, 0.f};
    float4v o1 = float4v{0.f, 0.f, 0.f, 0.f};
    #pragma unroll
    for (int ks = 0; ks < 7; ++ks) {
      short8v pa = *(const short8v*)(Pw + (lane & 15) * 472 + ks * 64 + ((lane >> 4) << 4));
      int kc = ks * 4 + (lane >> 4);
      int d0 = (lane & 15);
      int d1 = 16 + (lane & 15);
      short8v v0 = *(const short8v*)(sV + d0 * 448 + ((kc ^ swz4(d0)) << 4));
      short8v v1 = *(const short8v*)(sV + d1 * 448 + ((kc ^ swz4(d1)) << 4));
      mfma16x16(o0, pa, v0);
      mfma16x16(o1, pa, v1);
    }
    asm volatile("s_nop 7\n\ts_nop 7");

    #pragma unroll
    for (int r = 0; r < 4; ++r) {
      int trow = mt * 16 + ((lane >> 4) << 2) + r;
      if (trow < NTOK) {
        size_t ob = ((size_t)b * NTOK + trow) * CCH + h * HD + (lane & 15);
        o_t[ob] = __float2bfloat16(o0[r]);
        o_t[ob + 16] = __float2bfloat16(o1[r]);
      }
    }
  }
}

// ---------------- depthwise 7x7 conv (+BN in, +fBN out) ----------------

__global__ __launch_bounds__(64) void dwconv_kernel(
    const float* __restrict__ x1, const float* __restrict__ dw_w,
    const float* __restrict__ bn_s, const float* __restrict__ bn_t,
    const float* __restrict__ fbn_s, const float* __restrict__ fbn_t,
    __hip_bfloat16* __restrict__ y_c) {
  const int bc = blockIdx.x;          // b*512 + c
  const int c = bc & 511;
  __shared__ float img[196];
  __shared__ float wgt[49];
  const int lane = threadIdx.x;
  const float s = bn_s[c], t = bn_t[c];
  for (int i = lane; i < 196; i += 64)
    img[i] = x1[(size_t)bc * 196 + i] * s + t;
  if (lane < 49) wgt[lane] = dw_w[c * 49 + lane];
  __syncthreads();
  const float fs = fbn_s[c], ft = fbn_t[c];
  for (int p = lane; p < 196; p += 64) {
    int py = p / 14, px = p - py * 14;
    float acc = 0.f;
    #pragma unroll
    for (int dy = 0; dy < 7; ++dy) {
      int iy = py + dy - 3;
      if ((unsigned)iy < 14u) {
        #pragma unroll
        for (int dx = 0; dx < 7; ++dx) {
          int ix = px + dx - 3;
          if ((unsigned)ix < 14u) acc = fmaf(img[iy * 14 + ix], wgt[dy * 7 + dx], acc);
        }
      }
    }
    y_c[(size_t)bc * 196 + p] = __float2bfloat16(acc * fs + ft);
  }
}

// ---------------- launch ----------------

extern "C" void kernel_launch(void* const* d_in, const int* in_sizes, int n_in,
                              void* d_out, int out_size, void* d_ws, size_t ws_size,
                              hipStream_t stream) {
  const float* x      = (const float*)d_in[0];
  const float* bn_g   = (const float*)d_in[1];
  const float* bn_b   = (const float*)d_in[2];
  const float* bn_m   = (const float*)d_in[3];
  const float* bn_v   = (const float*)d_in[4];
  const float* qkv_w  = (const float*)d_in[5];
  const float* proj_w = (const float*)d_in[6];
  const float* proj_b = (const float*)d_in[7];
  const float* dw_w   = (const float*)d_in[8];
  const float* fbn_g  = (const float*)d_in[9];
  const float* fbn_b  = (const float*)d_in[10];
  const float* fbn_m  = (const float*)d_in[11];
  const float* fbn_v  = (const float*)d_in[12];
  const float* fc1_w  = (const float*)d_in[13];
  const float* fc1_b  = (const float*)d_in[14];
  const float* fc2_w  = (const float*)d_in[15];
  const float* fc2_b  = (const float*)d_in[16];
  const float* ls1    = (const float*)d_in[17];
  const float* ls2    = (const float*)d_in[18];

  char* ws = (char*)d_ws;
  float* cst             = (float*)ws;                              // 8 KB
  __hip_bfloat16* qkvb   = (__hip_bfloat16*)(ws + 8192);            // 1.5 MB
  __hip_bfloat16* projb  = (__hip_bfloat16*)(ws + 1581056);         // 0.5 MB
  __hip_bfloat16* fc1b   = (__hip_bfloat16*)(ws + 2105344);         // 2 MB
  __hip_bfloat16* fc2b   = (__hip_bfloat16*)(ws + 4202496);         // 2 MB
  __hip_bfloat16* xnt    = (__hip_bfloat16*)(ws + 6299648);         // 12.85 MB (also y_t)
  __hip_bfloat16* qkvt   = (__hip_bfloat16*)(ws + 19144704);        // 51.4 MB (also h)
  __hip_bfloat16* ot     = (__hip_bfloat16*)(ws + 70524928);        // 12.85 MB (also y_c)
  float* x1              = (float*)(ws + 83369984);                 // 25.7 MB  (end 109060096)

  prep_consts<<<dim3(2), dim3(256), 0, stream>>>(bn_g, bn_b, bn_m, bn_v,
                                                 fbn_g, fbn_b, fbn_m, fbn_v, cst);
  cvt_weights<<<dim3(3072), dim3(256), 0, stream>>>(qkv_w, proj_w, fc1_w, fc2_w,
                                                    qkvb, projb, fc1b, fc2b);
  transpose_cn<true><<<dim3(7, 16, 64), dim3(256), 0, stream>>>(x, xnt, cst, cst + 512);
  gemm_bt<0><<<dim3(98, 12), dim3(256), 0, stream>>>(xnt, qkvb, 1536, 512,
                                                     qkvt, nullptr, nullptr, nullptr, nullptr);
  attn_kernel<<<dim3(1024), dim3(256), 0, stream>>>(qkvt, ot);
  gemm_bt<1><<<dim3(98, 4), dim3(256), 0, stream>>>(ot, projb, 512, 512,
                                                    nullptr, x1, proj_b, ls1, x);
  dwconv_kernel<<<dim3(NB * CCH), dim3(64), 0, stream>>>(x1, dw_w, cst, cst + 512,
                                                         cst + 1024, cst + 1536, ot);
  transpose_cn<false><<<dim3(7, 16, 64), dim3(256), 0, stream>>>(ot, xnt, nullptr, nullptr);
  gemm_bt<2><<<dim3(98, 16), dim3(256), 0, stream>>>(xnt, fc1b, 2048, 512,
                                                     qkvt, nullptr, fc1_b, nullptr, nullptr);
  gemm_bt<3><<<dim3(98, 4), dim3(256), 0, stream>>>(qkvt, fc2b, 512, 2048,
                                                    nullptr, (float*)d_out, fc2_b, ls2, x1);
}

// Round 2
// 245.174 us; speedup vs baseline: 1.2512x; 1.2512x over previous
//
#include <hip/hip_runtime.h>
#include <hip/hip_bf16.h>
#include <stdint.h>

#define NTOK 196
#define NB   64
#define CCH  512
#define HID  2048
#define MTOT (NB * NTOK)   // 12544

typedef __attribute__((ext_vector_type(8))) short  short8v;
typedef __attribute__((ext_vector_type(4))) float  float4v;

// ---------------- helpers ----------------

__device__ __forceinline__ void mfma16x16(float4v& d, short8v a, short8v b) {
  asm("v_mfma_f32_16x16x32_bf16 %0, %1, %2, %0" : "+v"(d) : "v"(a), "v"(b));
}

__device__ __forceinline__ void gload_lds16(const void* gsrc, void* ldst) {
  __builtin_amdgcn_global_load_lds(
      (const __attribute__((address_space(1))) unsigned int*)gsrc,
      (__attribute__((address_space(3))) unsigned int*)ldst, 16, 0, 0);
}

__device__ __forceinline__ int swz4(int r) { return (r ^ (r >> 2)) & 3; }

// ---------------- prep: BN constants ----------------

__global__ void prep_consts(const float* __restrict__ bn_g, const float* __restrict__ bn_b,
                            const float* __restrict__ bn_m, const float* __restrict__ bn_v,
                            const float* __restrict__ fbn_g, const float* __restrict__ fbn_b,
                            const float* __restrict__ fbn_m, const float* __restrict__ fbn_v,
                            float* __restrict__ cst) {
  int c = blockIdx.x * blockDim.x + threadIdx.x;
  if (c < CCH) {
    float i1 = bn_g[c] * rsqrtf(bn_v[c] + 1e-5f);
    cst[c] = i1;
    cst[512 + c] = bn_b[c] - bn_m[c] * i1;
    float i2 = fbn_g[c] * rsqrtf(fbn_v[c] + 1e-5f);
    cst[1024 + c] = i2;
    cst[1536 + c] = fbn_b[c] - fbn_m[c] * i2;
  }
}

// ---------------- weights fp32 -> bf16 ----------------

__global__ void cvt_weights(const float* __restrict__ qkv_w, const float* __restrict__ proj_w,
                            const float* __restrict__ fc1_w, const float* __restrict__ fc2_w,
                            __hip_bfloat16* __restrict__ qkvb, __hip_bfloat16* __restrict__ projb,
                            __hip_bfloat16* __restrict__ fc1b, __hip_bfloat16* __restrict__ fc2b) {
  int i4 = blockIdx.x * blockDim.x + threadIdx.x;    // unit = 4 floats
  const int nq = 1536 * 512 / 4;
  const int np = 512 * 512 / 4;
  const int n1 = 2048 * 512 / 4;
  const float* src;
  __hip_bfloat16* dst;
  int k;
  if (i4 < nq)                { src = qkv_w;  dst = qkvb;  k = i4; }
  else if (i4 < nq + np)      { src = proj_w; dst = projb; k = i4 - nq; }
  else if (i4 < nq + np + n1) { src = fc1_w;  dst = fc1b;  k = i4 - nq - np; }
  else                        { src = fc2_w;  dst = fc2b;  k = i4 - nq - np - n1; }
  float4v v = *(const float4v*)(src + 4 * (size_t)k);
  #pragma unroll
  for (int l = 0; l < 4; ++l) dst[4 * (size_t)k + l] = __float2bfloat16(v[l]);
}

// ---------------- transpose NCHW fp32 -> token-major bf16 (raw + BN'd) ----------------

__global__ __launch_bounds__(256) void transpose_x(
    const float* __restrict__ x, __hip_bfloat16* __restrict__ xnt,
    __hip_bfloat16* __restrict__ xt, const float* __restrict__ cst) {
  __shared__ float tile[32][33];
  const int n0 = blockIdx.x * 32;
  const int c0 = blockIdx.y * 32;
  const int b  = blockIdx.z;
  const int j = threadIdx.x & 31, i = threadIdx.x >> 5;
  #pragma unroll
  for (int p = 0; p < 4; ++p) {
    int cc = c0 + i + p * 8;
    int n = n0 + j;
    if (n < NTOK) tile[i + p * 8][j] = x[((size_t)b * CCH + cc) * NTOK + n];
  }
  __syncthreads();
  const float s = cst[c0 + j], t = cst[512 + c0 + j];
  #pragma unroll
  for (int p = 0; p < 4; ++p) {
    int n = n0 + i + p * 8;
    int cc = c0 + j;
    if (n < NTOK) {
      float raw = tile[j][i + p * 8];
      size_t o = ((size_t)b * NTOK + n) * CCH + cc;
      xt[o]  = __float2bfloat16(raw);
      xnt[o] = __float2bfloat16(raw * s + t);
    }
  }
}

// ---------------- GEMM: C[M,N] = A[M,K] * B[N,K]^T, bf16 in, fp32 acc ----------------
// Triple-buffered, counted-vmcnt pipeline, raw s_barrier.
// EPI: 0 = plain bf16 store (QKV)
//      1 = proj: x1t = xt + ls1*(v+bias)            (token-major bf16, coalesced)
//      2 = fc1:  gelu(v+bias) bf16                  (token-major)
//      3 = fc2:  out = x1t + ls2*(v+bias) -> NCHW fp32 via in-LDS transpose

template<int EPI>
__global__ __launch_bounds__(256, 3) void gemm_bt(
    const __hip_bfloat16* __restrict__ A, const __hip_bfloat16* __restrict__ Bw,
    int N, int K, int NY,
    __hip_bfloat16* __restrict__ outb, float* __restrict__ outf,
    const float* __restrict__ bias, const float* __restrict__ ls,
    const __hip_bfloat16* __restrict__ resid) {
  __shared__ char lds[49152];   // 3 bufs x (A 8KB + B 8KB)
  const int tid  = threadIdx.x;
  const int lane = tid & 63;
  const int wave = tid >> 6;

  // bijective XCD swizzle (nwg % 8 == 0 for all our grids), y-fastest linearization
  const int q    = (int)gridDim.x >> 3;
  const int orig = blockIdx.x;
  const int wgid = (orig & 7) * q + (orig >> 3);
  const int bx = wgid / NY;
  const int by = wgid - bx * NY;

  const int m0 = bx * 128;
  const int n0 = by * 128;
  const int wm = (wave >> 1) * 64;
  const int wn = (wave & 1) * 64;
  const int KT = K >> 5;

  float4v acc[4][4] = {};

  auto stage = [&](int buf, int kt) {
    const int kb = kt * 32;
    char* base = lds + buf * 16384;
    #pragma unroll
    for (int i = 0; i < 2; ++i) {
      int L = i * 4096 + tid * 16;
      int row = L >> 6;
      int kc = ((L >> 4) & 3) ^ swz4(row);
      gload_lds16(A + (size_t)(m0 + row) * K + kb + kc * 8, base + L);
    }
    #pragma unroll
    for (int i = 0; i < 2; ++i) {
      int L = i * 4096 + tid * 16;
      int row = L >> 6;
      int kc = ((L >> 4) & 3) ^ swz4(row);
      gload_lds16(Bw + (size_t)(n0 + row) * K + kb + kc * 8, base + 8192 + L);
    }
  };

  auto compute = [&](int buf) {
    const char* bA = lds + buf * 16384;
    const char* bB = bA + 8192;
    short8v av[4], bv[4];
    #pragma unroll
    for (int t = 0; t < 4; ++t) {
      int row = wm + t * 16 + (lane & 15);
      int pc = (lane >> 4) ^ swz4(row);
      av[t] = *(const short8v*)(bA + row * 64 + pc * 16);
    }
    #pragma unroll
    for (int t = 0; t < 4; ++t) {
      int row = wn + t * 16 + (lane & 15);
      int pc = (lane >> 4) ^ swz4(row);
      bv[t] = *(const short8v*)(bB + row * 64 + pc * 16);
    }
    #pragma unroll
    for (int i = 0; i < 4; ++i)
      #pragma unroll
      for (int j = 0; j < 4; ++j)
        mfma16x16(acc[i][j], av[i], bv[j]);
  };

  // prologue: 2 tiles in flight (8 gload_lds per wave)
  stage(0, 0);
  stage(1, 1);
  int cur = 0;
  for (int kt = 0; kt < KT - 1; ++kt) {
    asm volatile("s_waitcnt vmcnt(4)" ::: "memory");   // oldest stage (buf cur) complete
    __builtin_amdgcn_s_barrier();                       // all waves' cur-stage complete
    __builtin_amdgcn_sched_barrier(0);
    if (kt + 2 < KT) {
      int s = cur + 2; if (s >= 3) s -= 3;
      stage(s, kt + 2);
    }
    compute(cur);
    ++cur; if (cur == 3) cur = 0;
  }
  asm volatile("s_waitcnt vmcnt(0)" ::: "memory");
  __builtin_amdgcn_s_barrier();
  __builtin_amdgcn_sched_barrier(0);
  compute(cur);
  asm volatile("s_nop 7\n\ts_nop 7");      // MFMA->VALU hazard guard

  if (EPI == 0 || EPI == 2) {
    #pragma unroll
    for (int i = 0; i < 4; ++i)
      #pragma unroll
      for (int j = 0; j < 4; ++j)
        #pragma unroll
        for (int r = 0; r < 4; ++r) {
          int m = m0 + wm + i * 16 + ((lane >> 4) << 2) + r;
          int n = n0 + wn + j * 16 + (lane & 15);
          float v = acc[i][j][r];
          if (EPI == 0) {
            outb[(size_t)m * N + n] = __float2bfloat16(v);
          } else {
            float z = v + bias[n];
            float g = 0.5f * z * (1.0f + erff(z * 0.70710678118654752f));
            outb[(size_t)m * N + n] = __float2bfloat16(g);
          }
        }
  } else if (EPI == 1) {
    #pragma unroll
    for (int i = 0; i < 4; ++i)
      #pragma unroll
      for (int j = 0; j < 4; ++j)
        #pragma unroll
        for (int r = 0; r < 4; ++r) {
          int m = m0 + wm + i * 16 + ((lane >> 4) << 2) + r;
          int n = n0 + wn + j * 16 + (lane & 15);
          float v = acc[i][j][r] + bias[n];
          v = __bfloat162float(resid[(size_t)m * CCH + n]) + ls[n] * v;
          outb[(size_t)m * CCH + n] = __float2bfloat16(v);
        }
  } else {   // EPI == 3 : fused epilogue + in-LDS transpose -> NCHW fp32
    float* LT = (float*)lds;   // [64][129] fp32
    #pragma unroll 1
    for (int hh = 0; hh < 2; ++hh) {
      __syncthreads();
      if ((wn >> 6) == hh) {
        #pragma unroll
        for (int i = 0; i < 4; ++i)
          #pragma unroll
          for (int j = 0; j < 4; ++j)
            #pragma unroll
            for (int r = 0; r < 4; ++r) {
              int ml = wm + i * 16 + ((lane >> 4) << 2) + r;
              int nl = j * 16 + (lane & 15);
              int n = n0 + wn + nl;
              float v = acc[i][j][r] + bias[n];
              v = __bfloat162float(resid[(size_t)(m0 + ml) * CCH + n]) + ls[n] * v;
              LT[nl * 129 + ml] = v;
            }
      }
      __syncthreads();
      {
        int ml0 = lane << 1;
        int mg = m0 + ml0;
        int bb0 = mg / NTOK;
        int tt0 = mg - bb0 * NTOK;
        int bb1 = (mg + 1) / NTOK;
        int tt1 = (mg + 1) - bb1 * NTOK;
        size_t base0 = (size_t)bb0 * (CCH * NTOK) + tt0;
        size_t base1 = (size_t)bb1 * (CCH * NTOK) + tt1;
        #pragma unroll
        for (int u = 0; u < 16; ++u) {
          int cr = wave * 16 + u;
          int cg = n0 + hh * 64 + cr;
          float v0 = LT[cr * 129 + ml0];
          float v1 = LT[cr * 129 + ml0 + 1];
          outf[base0 + (size_t)cg * NTOK] = v0;
          outf[base1 + (size_t)cg * NTOK] = v1;
        }
      }
    }
  }
}

// ---------------- attention: one block per (batch, head) ----------------

__global__ __launch_bounds__(256, 2) void attn_kernel(
    const __hip_bfloat16* __restrict__ qkv, __hip_bfloat16* __restrict__ o_t) {
  __shared__ char sQ[208 * 64];    // [208][32] bf16, chunk-swizzled rows
  __shared__ char sK[224 * 64];    // [224][32] bf16
  __shared__ char sV[32 * 448];    // V^T [32][224] bf16, chunk-swizzled
  __shared__ char sP[4][16 * 472]; // per-wave P [16][236] bf16
  const int tid  = threadIdx.x;
  const int lane = tid & 63;
  const int wave = tid >> 6;
  const int b = blockIdx.x >> 4;
  const int h = blockIdx.x & 15;
  const size_t qbase = (size_t)b * NTOK * 1536 + h * 32;

  {
    uint32_t* z = (uint32_t*)sQ;
    for (int i = tid; i < (208 * 64) / 4; i += 256) z[i] = 0u;
    z = (uint32_t*)sK;
    for (int i = tid; i < (224 * 64) / 4; i += 256) z[i] = 0u;
    z = (uint32_t*)sV;
    for (int i = tid; i < (32 * 448) / 4; i += 256) z[i] = 0u;
  }
  __syncthreads();

  for (int p = tid; p < NTOK * 4; p += 256) {
    int row = p >> 2, c = p & 3;
    const __hip_bfloat16* src = qkv + qbase + (size_t)row * 1536 + c * 8;
    short8v q = *(const short8v*)(src);
    short8v k = *(const short8v*)(src + 512);
    short8v v = *(const short8v*)(src + 1024);
    int pc = c ^ swz4(row);
    *(short8v*)(sQ + row * 64 + pc * 16) = q;
    *(short8v*)(sK + row * 64 + pc * 16) = k;
    #pragma unroll
    for (int j = 0; j < 8; ++j) {
      int d = c * 8 + j;
      int ch = (row >> 3) ^ swz4(d);
      *(uint16_t*)(sV + d * 448 + ch * 16 + (row & 7) * 2) = (uint16_t)v[j];
    }
  }
  __syncthreads();

  const float scale = 0.17677669529663687f;   // 1/sqrt(32)
  char* Pw = sP[wave];

  for (int mt = wave; mt < 13; mt += 4) {
    int qrow = mt * 16 + (lane & 15);
    int pcq = (lane >> 4) ^ swz4(qrow);
    short8v aq = *(const short8v*)(sQ + qrow * 64 + pcq * 16);

    float4v s[14];
    #pragma unroll
    for (int nt = 0; nt < 14; ++nt) {
      int krow = nt * 16 + (lane & 15);
      int pck = (lane >> 4) ^ swz4(krow);
      short8v bk = *(const short8v*)(sK + krow * 64 + pck * 16);
      s[nt] = float4v{0.f, 0.f, 0.f, 0.f};
      mfma16x16(s[nt], aq, bk);
    }
    asm volatile("s_nop 7\n\ts_nop 7");

    float mx[4] = {-INFINITY, -INFINITY, -INFINITY, -INFINITY};
    #pragma unroll
    for (int nt = 0; nt < 14; ++nt) {
      bool valid = (nt * 16 + (lane & 15)) < NTOK;
      #pragma unroll
      for (int r = 0; r < 4; ++r) {
        float v = valid ? s[nt][r] * scale : -INFINITY;
        s[nt][r] = v;
        mx[r] = fmaxf(mx[r], v);
      }
    }
    #pragma unroll
    for (int off = 1; off < 16; off <<= 1) {
      #pragma unroll
      for (int r = 0; r < 4; ++r) mx[r] = fmaxf(mx[r], __shfl_xor(mx[r], off));
    }
    float sum[4] = {0.f, 0.f, 0.f, 0.f};
    #pragma unroll
    for (int nt = 0; nt < 14; ++nt) {
      #pragma unroll
      for (int r = 0; r < 4; ++r) {
        float e = __expf(s[nt][r] - mx[r]);
        s[nt][r] = e;
        sum[r] += e;
      }
    }
    #pragma unroll
    for (int off = 1; off < 16; off <<= 1) {
      #pragma unroll
      for (int r = 0; r < 4; ++r) sum[r] += __shfl_xor(sum[r], off);
    }
    float rs[4];
    #pragma unroll
    for (int r = 0; r < 4; ++r) rs[r] = 1.0f / sum[r];

    #pragma unroll
    for (int nt = 0; nt < 14; ++nt) {
      int col = nt * 16 + (lane & 15);
      #pragma unroll
      for (int r = 0; r < 4; ++r) {
        int prow = ((lane >> 4) << 2) + r;
        *(__hip_bfloat16*)(Pw + prow * 472 + col * 2) = __float2bfloat16(s[nt][r] * rs[r]);
      }
    }

    float4v o0 = float4v{0.f, 0.f, 0.f, 0.f};
    float4v o1 = float4v{0.f, 0.f, 0.f, 0.f};
    #pragma unroll
    for (int ks = 0; ks < 7; ++ks) {
      short8v pa = *(const short8v*)(Pw + (lane & 15) * 472 + ks * 64 + ((lane >> 4) << 4));
      int kc = ks * 4 + (lane >> 4);
      int d0 = (lane & 15);
      int d1 = 16 + (lane & 15);
      short8v v0 = *(const short8v*)(sV + d0 * 448 + ((kc ^ swz4(d0)) << 4));
      short8v v1 = *(const short8v*)(sV + d1 * 448 + ((kc ^ swz4(d1)) << 4));
      mfma16x16(o0, pa, v0);
      mfma16x16(o1, pa, v1);
    }
    asm volatile("s_nop 7\n\ts_nop 7");

    #pragma unroll
    for (int r = 0; r < 4; ++r) {
      int trow = mt * 16 + ((lane >> 4) << 2) + r;
      if (trow < NTOK) {
        size_t ob = ((size_t)b * NTOK + trow) * CCH + h * 32 + (lane & 15);
        o_t[ob] = __float2bfloat16(o0[r]);
        o_t[ob + 16] = __float2bfloat16(o1[r]);
      }
    }
  }
}

// ---------------- depthwise 7x7 conv, token-major (+BN in, +fBN out) ----------------

__global__ __launch_bounds__(448) void dwconv_tm(
    const __hip_bfloat16* __restrict__ x1t, const float* __restrict__ dw_w,
    const float* __restrict__ cst, __hip_bfloat16* __restrict__ yt) {
  __shared__ float img[196][32];
  __shared__ float wgt[49][32];
  const int tid = threadIdx.x;
  const int b  = blockIdx.x >> 4;
  const int cb = (blockIdx.x & 15) * 32;
  const int c  = tid & 31;
  const int gc = cb + c;
  const float s = cst[gc], t0 = cst[512 + gc];
  #pragma unroll
  for (int k = 0; k < 14; ++k) {
    int p = (tid >> 5) + k * 14;
    img[p][c] = __bfloat162float(x1t[((size_t)b * NTOK + p) * CCH + gc]) * s + t0;
  }
  for (int i = tid; i < 49 * 32; i += 448) {
    int tap = i >> 5, cc = i & 31;
    wgt[tap][cc] = dw_w[(cb + cc) * 49 + tap];
  }
  __syncthreads();

  const int px = tid >> 5;        // 0..13
  float out[14];
  #pragma unroll
  for (int i = 0; i < 14; ++i) out[i] = 0.f;
  #pragma unroll 1
  for (int row = 0; row < 14; ++row) {
    float v[7];
    #pragma unroll
    for (int dx = 0; dx < 7; ++dx) {
      int ix = px + dx - 3;
      v[dx] = ((unsigned)ix < 14u) ? img[row * 14 + ix][c] : 0.f;
    }
    #pragma unroll
    for (int kk = 0; kk < 7; ++kk) {
      int py = row + 3 - kk;
      if (py >= 0 && py < 14) {
        float hsum = 0.f;
        #pragma unroll
        for (int dx = 0; dx < 7; ++dx) hsum = fmaf(v[dx], wgt[kk * 7 + dx][c], hsum);
        out[py] += hsum;
      }
    }
  }
  const float fs = cst[1024 + gc], ft = cst[1536 + gc];
  #pragma unroll
  for (int py = 0; py < 14; ++py)
    yt[((size_t)b * NTOK + py * 14 + px) * CCH + gc] = __float2bfloat16(out[py] * fs + ft);
}

// ---------------- launch ----------------

extern "C" void kernel_launch(void* const* d_in, const int* in_sizes, int n_in,
                              void* d_out, int out_size, void* d_ws, size_t ws_size,
                              hipStream_t stream) {
  const float* x      = (const float*)d_in[0];
  const float* bn_g   = (const float*)d_in[1];
  const float* bn_b   = (const float*)d_in[2];
  const float* bn_m   = (const float*)d_in[3];
  const float* bn_v   = (const float*)d_in[4];
  const float* qkv_w  = (const float*)d_in[5];
  const float* proj_w = (const float*)d_in[6];
  const float* proj_b = (const float*)d_in[7];
  const float* dw_w   = (const float*)d_in[8];
  const float* fbn_g  = (const float*)d_in[9];
  const float* fbn_b  = (const float*)d_in[10];
  const float* fbn_m  = (const float*)d_in[11];
  const float* fbn_v  = (const float*)d_in[12];
  const float* fc1_w  = (const float*)d_in[13];
  const float* fc1_b  = (const float*)d_in[14];
  const float* fc2_w  = (const float*)d_in[15];
  const float* fc2_b  = (const float*)d_in[16];
  const float* ls1    = (const float*)d_in[17];
  const float* ls2    = (const float*)d_in[18];

  char* ws = (char*)d_ws;
  float* cst             = (float*)ws;                       // 8 KB
  __hip_bfloat16* qkvb   = (__hip_bfloat16*)(ws + 8192);
  __hip_bfloat16* projb  = (__hip_bfloat16*)(ws + 1581056);
  __hip_bfloat16* fc1b   = (__hip_bfloat16*)(ws + 2105344);
  __hip_bfloat16* fc2b   = (__hip_bfloat16*)(ws + 4202496);
  __hip_bfloat16* xnt    = (__hip_bfloat16*)(ws + 6299648);   // 12.85 MB
  __hip_bfloat16* xt     = (__hip_bfloat16*)(ws + 19144704);  // 12.85 MB
  __hip_bfloat16* qkvt   = (__hip_bfloat16*)(ws + 31989760);  // 38.5 MB
  __hip_bfloat16* ot     = (__hip_bfloat16*)(ws + 70524928);  // 12.85 MB
  __hip_bfloat16* x1t    = (__hip_bfloat16*)(ws + 83369984);  // 12.85 MB
  __hip_bfloat16* yt     = (__hip_bfloat16*)(ws + 96215040);  // 12.85 MB (end 109060096)
  __hip_bfloat16* hbuf   = (__hip_bfloat16*)(ws + 6299648);   // 51.4 MB overlay (xnt/xt/qkvt dead)

  prep_consts<<<dim3(2), dim3(256), 0, stream>>>(bn_g, bn_b, bn_m, bn_v,
                                                 fbn_g, fbn_b, fbn_m, fbn_v, cst);
  cvt_weights<<<dim3(3072), dim3(256), 0, stream>>>(qkv_w, proj_w, fc1_w, fc2_w,
                                                    qkvb, projb, fc1b, fc2b);
  transpose_x<<<dim3(7, 16, 64), dim3(256), 0, stream>>>(x, xnt, xt, cst);
  // QKV: M=12544, N=1536, K=512 ; grid 98*12 = 1176
  gemm_bt<0><<<dim3(1176), dim3(256), 0, stream>>>(xnt, qkvb, 1536, 512, 12,
                                                   qkvt, nullptr, nullptr, nullptr, nullptr);
  attn_kernel<<<dim3(1024), dim3(256), 0, stream>>>(qkvt, ot);
  // proj: N=512, K=512 ; grid 98*4 = 392
  gemm_bt<1><<<dim3(392), dim3(256), 0, stream>>>(ot, projb, 512, 512, 4,
                                                  x1t, nullptr, proj_b, ls1, xt);
  dwconv_tm<<<dim3(1024), dim3(448), 0, stream>>>(x1t, dw_w, cst, yt);
  // fc1: N=2048, K=512 ; grid 98*16 = 1568
  gemm_bt<2><<<dim3(1568), dim3(256), 0, stream>>>(yt, fc1b, 2048, 512, 16,
                                                   hbuf, nullptr, fc1_b, nullptr, nullptr);
  // fc2: N=512, K=2048 ; grid 98*4 = 392 ; writes NCHW fp32 d_out
  gemm_bt<3><<<dim3(392), dim3(256), 0, stream>>>(hbuf, fc2b, 512, 2048, 4,
                                                  nullptr, (float*)d_out, fc2_b, ls2, x1t);
}